// Round 6
// baseline (749.688 us; speedup 1.0000x reference)
//
#include <hip/hip_runtime.h>

typedef __bf16 bf16x8 __attribute__((ext_vector_type(8)));
typedef float  f32x4  __attribute__((ext_vector_type(4)));

// ---------------- bf16x2 split helper: pack(hi | lo<<16) ----------------
__device__ __forceinline__ unsigned int splitpack(float x) {
  unsigned int u = __float_as_uint(x);
  unsigned int hi = (u + 0x7fffu + ((u >> 16) & 1u)) >> 16;
  float l = x - __uint_as_float(hi << 16);
  unsigned int ul = __float_as_uint(l);
  unsigned int lo = (ul + 0x7fffu + ((ul >> 16) & 1u)) >> 16;
  return hi | (lo << 16);
}

__device__ __forceinline__ void mfma_bf16(f32x4& d, uint4 a, uint4 b) {
  d = __builtin_amdgcn_mfma_f32_16x16x32_bf16(
        __builtin_bit_cast(bf16x8, a), __builtin_bit_cast(bf16x8, b), d, 0, 0, 0);
}

// ======== layouts ========
// h1p u32: IDX1(b,g,t,pl,r,c,j) = b*8388608 + g*524288 + t*32768 + pl*8192 + (r*32+c)*8 + j
// h2p u32: IDX2(b,g,t,pl,r,c,j) = b*4194304 + g*131072 + t*8192 + pl*2048 + (r*16+c)*8 + j

// ---------------- conv1: VALU conv, epilogue writes j-grouped parity planes ------------
__global__ void conv1_k(const float* __restrict__ in, const float* __restrict__ wgt,
                        const float* __restrict__ bias, unsigned int* __restrict__ h1p) {
  const int tx = threadIdx.x;          // 0..15
  const int w0 = tx * 4;
  const int h  = blockIdx.x * 16 + threadIdx.y;  // 0..63
  const int co0 = blockIdx.y * 8;
  const int bz = blockIdx.z;
  const int b = bz >> 4, t = bz & 15;

  float acc[8][4];
  #pragma unroll
  for (int i = 0; i < 8; ++i) {
    const float bv = bias[co0 + i];
    #pragma unroll
    for (int j = 0; j < 4; ++j) acc[i][j] = bv;
  }
  const int cs = 2 * w0 - 2;

  for (int ci = 0; ci < 3; ++ci) {
    const float* inc = in + (size_t)((b * 3 + ci) * 16) * (128 * 128);
    const float* wc  = wgt + ((size_t)co0 * 3 + ci) * 27;
    #pragma unroll
    for (int kd = 0; kd < 3; ++kd) {
      const int t2 = t - 1 + kd;
      if (t2 < 0 || t2 >= 16) continue;
      const float* ip = inc + t2 * (128 * 128);
      #pragma unroll
      for (int kh = 0; kh < 3; ++kh) {
        const int hh = 2 * h - 1 + kh;
        float v[10];
        if (hh >= 0) {
          const float* r = ip + hh * 128 + cs;
          if (cs >= 0) { float2 u = *(const float2*)r; v[0] = u.x; v[1] = u.y; }
          else         { v[0] = 0.f; v[1] = 0.f; }
          float2 u1 = *(const float2*)(r + 2); v[2] = u1.x; v[3] = u1.y;
          float2 u2 = *(const float2*)(r + 4); v[4] = u2.x; v[5] = u2.y;
          float2 u3 = *(const float2*)(r + 6); v[6] = u3.x; v[7] = u3.y;
          float2 u4 = *(const float2*)(r + 8); v[8] = u4.x; v[9] = u4.y;
        } else {
          #pragma unroll
          for (int z = 0; z < 10; ++z) v[z] = 0.f;
        }
        #pragma unroll
        for (int i = 0; i < 8; ++i) {
          const float* wp = wc + (size_t)i * (3 * 27) + kd * 9 + kh * 3;
          const float wa = wp[0], wb = wp[1], wcc = wp[2];
          #pragma unroll
          for (int wi = 0; wi < 4; ++wi) {
            acc[i][wi] = fmaf(v[1 + 2*wi], wa,  acc[i][wi]);
            acc[i][wi] = fmaf(v[2 + 2*wi], wb,  acc[i][wi]);
            acc[i][wi] = fmaf(v[3 + 2*wi], wcc, acc[i][wi]);
          }
        }
      }
    }
  }
  const int ph = h & 1, rr = h >> 1, cc0 = tx * 2;
  const size_t base0 = (size_t)b * 8388608 + (size_t)blockIdx.y * 524288
                     + (size_t)t * 32768 + (size_t)(ph * 2) * 8192 + (size_t)rr * 256;
  #pragma unroll
  for (int i = 0; i < 8; ++i) {
    unsigned int p0 = splitpack(fmaxf(acc[i][0], 0.f));
    unsigned int p1 = splitpack(fmaxf(acc[i][1], 0.f));
    unsigned int p2 = splitpack(fmaxf(acc[i][2], 0.f));
    unsigned int p3 = splitpack(fmaxf(acc[i][3], 0.f));
    h1p[base0 + cc0 * 8 + i]              = p0;
    h1p[base0 + 8192 + cc0 * 8 + i]       = p1;
    h1p[base0 + (cc0 + 1) * 8 + i]        = p2;
    h1p[base0 + 8192 + (cc0 + 1) * 8 + i] = p3;
  }
}

// ---------------- w2 -> MFMA tiles [tap27][cic4][cbk2][kg4][col128][j8] ----------------
__global__ void split_w2_k(const float* __restrict__ w2, unsigned short* __restrict__ whi,
                           unsigned short* __restrict__ wlo) {
  unsigned int o = blockIdx.x * 256u + threadIdx.x;      // grid exact: 3456*256
  unsigned int j   = o & 7u;
  unsigned int col = (o >> 3) & 127u;
  unsigned int kg  = (o >> 10) & 3u;
  unsigned int cbk = (o >> 12) & 1u;
  unsigned int cic = (o >> 13) & 3u;
  unsigned int tap = o >> 15;
  unsigned int co = cbk * 128u + col, ci = cic * 32u + kg * 8u + j;
  float x = w2[((size_t)co * 128u + ci) * 27u + tap];
  unsigned int p = splitpack(x);
  whi[o] = (unsigned short)(p & 0xffffu);
  wlo[o] = (unsigned short)(p >> 16);
}

// ---------------- w3 -> MFMA tiles [tap27][cic8][cb4][kg4][col128][j8] ----------------
__global__ void split_w3_k(const float* __restrict__ w3, unsigned short* __restrict__ whi,
                           unsigned short* __restrict__ wlo) {
  unsigned int o = blockIdx.x * 256u + threadIdx.x;      // grid exact: 13824*256 = 27<<17
  unsigned int j   = o & 7u;
  unsigned int col = (o >> 3) & 127u;
  unsigned int kg  = (o >> 10) & 3u;
  unsigned int cb  = (o >> 12) & 3u;
  unsigned int cic = (o >> 14) & 7u;
  unsigned int tap = o >> 17;
  unsigned int co = cb * 128u + col, ci = cic * 32u + kg * 8u + j;
  float x = w3[((size_t)co * 256u + ci) * 27u + tap];
  unsigned int p = splitpack(x);
  whi[o] = (unsigned short)(p & 0xffffu);
  wlo[o] = (unsigned short)(p >> 16);
}

// ---------------- codebook -> tiled hi/lo ----------------
__global__ void split_cb_k(const float* __restrict__ cb, unsigned short* __restrict__ cbhi,
                           unsigned short* __restrict__ cblo) {
  unsigned int o = blockIdx.x * 256u + threadIdx.x;      // grid exact: 16384*256 = 2^22
  unsigned int j   = o & 7u;
  unsigned int row = (o >> 3) & 127u;
  unsigned int kq  = (o >> 10) & 3u;
  unsigned int kc  = (o >> 12) & 15u;
  unsigned int vb  = o >> 16;
  unsigned int v = vb * 128u + row, k = kc * 32u + kq * 8u + j;
  float x = cb[(size_t)v * 512u + k];
  unsigned int p = splitpack(x);
  cbhi[o] = (unsigned short)(p & 0xffffu);
  cblo[o] = (unsigned short)(p >> 16);
}

// ---------------- codebook squared norms ----------------
__global__ void c2_k(const float* __restrict__ cb, float* __restrict__ c2) {
  const int wid = threadIdx.x >> 6, lane = threadIdx.x & 63;
  const int v = blockIdx.x * 4 + wid;
  const float* row = cb + (size_t)v * 512 + lane * 8;
  float4 a = *(const float4*)row, b = *(const float4*)(row + 4);
  float s = a.x*a.x + a.y*a.y + a.z*a.z + a.w*a.w
          + b.x*b.x + b.y*b.y + b.z*b.z + b.w*b.w;
  #pragma unroll
  for (int off = 32; off; off >>= 1) s += __shfl_down(s, off);
  if (lane == 0) c2[v] = s;
}

// ---------------- conv2: MFMA, dbuf LDS, XCD-swizzled 1D grid (bt co-residency) -------
#define NCH2 108   // 27 taps * 4 ci-chunks of 32
#define BUFO 16384
__global__ __launch_bounds__(512) void conv2_mfma_k(
    const unsigned int* __restrict__ xp,
    const unsigned short* __restrict__ whi, const unsigned short* __restrict__ wlo,
    const float* __restrict__ bias,
    unsigned int* __restrict__ h2p) {
  __shared__ __align__(16) unsigned short lds[32768];

  const int tid  = threadIdx.x;
  const int lane = tid & 63;
  const int wid  = tid >> 6;
  const int wm   = wid >> 2, wn = wid & 3;
  // XCD swizzle: bid%8 -> bt-group; all 16 (cbk,nb) of a bt co-resident per XCD
  const int bid = blockIdx.x;          // 0..511
  const int xcd = bid & 7;
  const int q   = bid >> 3;            // 0..63
  const int cbk = q & 1;
  const int nb  = (q >> 1) & 7;
  const int bt  = xcd + 8 * (q >> 4);  // q>>4 in 0..3
  const int b = bt >> 4, t = bt & 15;

  const int skg = tid >> 7;
  const int sn  = tid & 127;
  const int s_hout = nb * 4 + (sn >> 5);
  const int s_wout = sn & 31;

  const int lc = lane & 15, kgl = lane >> 4;

  f32x4 acc[4][2];
  #pragma unroll
  for (int mf = 0; mf < 4; ++mf)
    #pragma unroll
    for (int nf = 0; nf < 2; ++nf) acc[mf][nf] = (f32x4)(0.f);

  auto issue = [&](int ic, uint4& xa, uint4& xb, uint4& wh, uint4& wl) {
    const int tap = ic >> 2, cic = ic & 3;
    const int kd = tap / 9, r9 = tap % 9;
    const int kh = r9 / 3, kw = r9 % 3;
    const int tt = t + kd - 1;
    const int pl = ((kh != 1) ? 2 : 0) + ((kw != 1) ? 1 : 0);
    const int r  = s_hout + (kh != 0) - 1;
    const int c  = s_wout + (kw != 0) - 1;
    const bool oob = (tt < 0) || (tt > 15) || (r < 0) || (c < 0);
    const int o = b * 8388608 + (cic * 4 + skg) * 524288 + tt * 32768 + pl * 8192 + (r * 32 + c) * 8;
    const unsigned int* src = xp + (oob ? 0 : o);
    uint4 a = *(const uint4*)src, bb = *(const uint4*)(src + 4);
    if (oob) { a = make_uint4(0u,0u,0u,0u); bb = make_uint4(0u,0u,0u,0u); }
    xa = a; xb = bb;
    const size_t slab = ((size_t)((tap * 4 + cic) * 2 + cbk)) << 12;
    wh = *(const uint4*)(whi + slab + tid * 8);
    wl = *(const uint4*)(wlo + slab + tid * 8);
  };

  auto stage = [&](int bo, const uint4& xa, const uint4& xb, const uint4& wh, const uint4& wl) {
    *(uint4*)&lds[bo + tid * 8] = wh;
    *(uint4*)&lds[bo + 4096 + tid * 8] = wl;
    uint4 H, L;
    H.x = (xa.x & 0xffffu) | (xa.y << 16);  L.x = (xa.x >> 16) | (xa.y & 0xffff0000u);
    H.y = (xa.z & 0xffffu) | (xa.w << 16);  L.y = (xa.z >> 16) | (xa.w & 0xffff0000u);
    H.z = (xb.x & 0xffffu) | (xb.y << 16);  L.z = (xb.x >> 16) | (xb.y & 0xffff0000u);
    H.w = (xb.z & 0xffffu) | (xb.w << 16);  L.w = (xb.z >> 16) | (xb.w & 0xffff0000u);
    *(uint4*)&lds[bo + 8192  + (skg * 128 + sn) * 8] = H;
    *(uint4*)&lds[bo + 12288 + (skg * 128 + sn) * 8] = L;
  };

  auto mma = [&](int bo) {
    uint4 ah[4], al[4], bh[2], bl[2];
    #pragma unroll
    for (int mf = 0; mf < 4; ++mf) {
      const int o = bo + kgl * 1024 + (wm * 64 + mf * 16 + lc) * 8;
      ah[mf] = *(const uint4*)&lds[o];
      al[mf] = *(const uint4*)&lds[o + 4096];
    }
    #pragma unroll
    for (int nf = 0; nf < 2; ++nf) {
      const int o = bo + 8192 + kgl * 1024 + (wn * 32 + nf * 16 + lc) * 8;
      bh[nf] = *(const uint4*)&lds[o];
      bl[nf] = *(const uint4*)&lds[o + 4096];
    }
    #pragma unroll
    for (int mf = 0; mf < 4; ++mf)
      #pragma unroll
      for (int nf = 0; nf < 2; ++nf) mfma_bf16(acc[mf][nf], ah[mf], bh[nf]);
    #pragma unroll
    for (int mf = 0; mf < 4; ++mf)
      #pragma unroll
      for (int nf = 0; nf < 2; ++nf) mfma_bf16(acc[mf][nf], ah[mf], bl[nf]);
    #pragma unroll
    for (int mf = 0; mf < 4; ++mf)
      #pragma unroll
      for (int nf = 0; nf < 2; ++nf) mfma_bf16(acc[mf][nf], al[mf], bh[nf]);
  };

  uint4 xa0, xb0, wh0, wl0, xa1, xb1, wh1, wl1;
  issue(0, xa0, xb0, wh0, wl0);
  issue(1, xa1, xb1, wh1, wl1);

  #pragma unroll 1
  for (int ic = 0; ic < NCH2; ic += 2) {
    stage(0, xa0, xb0, wh0, wl0);
    __syncthreads();
    if (ic + 2 < NCH2) issue(ic + 2, xa0, xb0, wh0, wl0);
    mma(0);
    stage(BUFO, xa1, xb1, wh1, wl1);
    __syncthreads();
    if (ic + 3 < NCH2) issue(ic + 3, xa1, xb1, wh1, wl1);
    mma(BUFO);
  }

  const int lr4 = (lane >> 4) * 4;
  #pragma unroll
  for (int mf = 0; mf < 4; ++mf) {
    const int co0g = cbk * 128 + wm * 64 + mf * 16 + lr4;
    const float4 bv = *(const float4*)(bias + co0g);
    const float* bp = (const float*)&bv;
    const size_t gbase = (size_t)(b * 32 + (co0g >> 3)) * 131072 + (size_t)t * 8192 + (co0g & 7);
    #pragma unroll
    for (int nf = 0; nf < 2; ++nf) {
      const int n_l = wn * 32 + nf * 16 + lc;
      const int h_out = nb * 4 + (n_l >> 5);
      const int w_out = n_l & 31;
      const int pl_o = ((h_out & 1) << 1) | (w_out & 1);
      const size_t sp = gbase + (size_t)pl_o * 2048 + (size_t)((h_out >> 1) * 16 + (w_out >> 1)) * 8;
      #pragma unroll
      for (int r = 0; r < 4; ++r) {
        const float x = fmaxf(acc[mf][nf][r] + bp[r], 0.f);
        h2p[sp + r] = splitpack(x);
      }
    }
  }
}

// ---------------- conv3: MFMA, dbuf LDS, XCD-swizzled 1D grid (bt co-residency) -------
#define NCH 216   // 27 taps * 8 ci-chunks of 32
__global__ __launch_bounds__(512) void conv3_mfma_k(
    const unsigned int* __restrict__ xp,
    const unsigned short* __restrict__ whi, const unsigned short* __restrict__ wlo,
    const float* __restrict__ bias,
    unsigned short* __restrict__ fhi, unsigned short* __restrict__ flo) {
  __shared__ __align__(16) unsigned short lds[32768];

  const int tid  = threadIdx.x;
  const int lane = tid & 63;
  const int wid  = tid >> 6;
  const int wm   = wid >> 2, wn = wid & 3;
  // XCD swizzle: bid%8 -> bt-group; all 8 (cb,hb) of a bt co-resident per XCD
  const int bid = blockIdx.x;          // 0..255
  const int xcd = bid & 7;
  const int q   = bid >> 3;            // 0..31
  const int cb  = q & 3;
  const int hb  = (q >> 2) & 1;
  const int bt  = xcd + 8 * (q >> 3);  // q>>3 in 0..3
  const int b = bt >> 4, t = bt & 15;

  const int skg = tid >> 7;
  const int sn  = tid & 127;
  const int shn = hb * 8 + (sn >> 4);
  const int swn = sn & 15;

  const int lc = lane & 15, kgl = lane >> 4;

  f32x4 acc[4][2];
  #pragma unroll
  for (int mf = 0; mf < 4; ++mf)
    #pragma unroll
    for (int nf = 0; nf < 2; ++nf) acc[mf][nf] = (f32x4)(0.f);

  auto issue = [&](int ic, uint4& xa, uint4& xb, uint4& wh, uint4& wl) {
    const int tap = ic >> 3, cic = ic & 7;
    const int kd = tap / 9, r9 = tap % 9;
    const int kh = r9 / 3, kw = r9 % 3;
    const int tt = t + kd - 1;
    const int pl = ((kh != 1) ? 2 : 0) + ((kw != 1) ? 1 : 0);
    const int r  = shn + (kh != 0) - 1;
    const int c  = swn + (kw != 0) - 1;
    const bool oob = (tt < 0) || (tt > 15) || (r < 0) || (c < 0);
    const int o = b * 4194304 + (cic * 4 + skg) * 131072 + tt * 8192 + pl * 2048 + (r * 16 + c) * 8;
    const unsigned int* src = xp + (oob ? 0 : o);
    uint4 a = *(const uint4*)src, bb = *(const uint4*)(src + 4);
    if (oob) { a = make_uint4(0u,0u,0u,0u); bb = make_uint4(0u,0u,0u,0u); }
    xa = a; xb = bb;
    const size_t slab = ((size_t)((tap * 8 + cic) * 4 + cb)) << 12;
    wh = *(const uint4*)(whi + slab + tid * 8);
    wl = *(const uint4*)(wlo + slab + tid * 8);
  };

  auto stage = [&](int bo, const uint4& xa, const uint4& xb, const uint4& wh, const uint4& wl) {
    *(uint4*)&lds[bo + tid * 8] = wh;
    *(uint4*)&lds[bo + 4096 + tid * 8] = wl;
    uint4 H, L;
    H.x = (xa.x & 0xffffu) | (xa.y << 16);  L.x = (xa.x >> 16) | (xa.y & 0xffff0000u);
    H.y = (xa.z & 0xffffu) | (xa.w << 16);  L.y = (xa.z >> 16) | (xa.w & 0xffff0000u);
    H.z = (xb.x & 0xffffu) | (xb.y << 16);  L.z = (xb.x >> 16) | (xb.y & 0xffff0000u);
    H.w = (xb.z & 0xffffu) | (xb.w << 16);  L.w = (xb.z >> 16) | (xb.w & 0xffff0000u);
    *(uint4*)&lds[bo + 8192  + (skg * 128 + sn) * 8] = H;
    *(uint4*)&lds[bo + 12288 + (skg * 128 + sn) * 8] = L;
  };

  auto mma = [&](int bo) {
    uint4 ah[4], al[4], bh[2], bl[2];
    #pragma unroll
    for (int mf = 0; mf < 4; ++mf) {
      const int o = bo + kgl * 1024 + (wm * 64 + mf * 16 + lc) * 8;
      ah[mf] = *(const uint4*)&lds[o];
      al[mf] = *(const uint4*)&lds[o + 4096];
    }
    #pragma unroll
    for (int nf = 0; nf < 2; ++nf) {
      const int o = bo + 8192 + kgl * 1024 + (wn * 32 + nf * 16 + lc) * 8;
      bh[nf] = *(const uint4*)&lds[o];
      bl[nf] = *(const uint4*)&lds[o + 4096];
    }
    #pragma unroll
    for (int mf = 0; mf < 4; ++mf)
      #pragma unroll
      for (int nf = 0; nf < 2; ++nf) mfma_bf16(acc[mf][nf], ah[mf], bh[nf]);
    #pragma unroll
    for (int mf = 0; mf < 4; ++mf)
      #pragma unroll
      for (int nf = 0; nf < 2; ++nf) mfma_bf16(acc[mf][nf], ah[mf], bl[nf]);
    #pragma unroll
    for (int mf = 0; mf < 4; ++mf)
      #pragma unroll
      for (int nf = 0; nf < 2; ++nf) mfma_bf16(acc[mf][nf], al[mf], bh[nf]);
  };

  uint4 xa0, xb0, wh0, wl0, xa1, xb1, wh1, wl1;
  issue(0, xa0, xb0, wh0, wl0);
  issue(1, xa1, xb1, wh1, wl1);

  #pragma unroll 1
  for (int ic = 0; ic < NCH; ic += 2) {
    stage(0, xa0, xb0, wh0, wl0);
    __syncthreads();
    if (ic + 2 < NCH) issue(ic + 2, xa0, xb0, wh0, wl0);
    mma(0);
    stage(BUFO, xa1, xb1, wh1, wl1);
    __syncthreads();
    if (ic + 3 < NCH) issue(ic + 3, xa1, xb1, wh1, wl1);
    mma(BUFO);
  }

  const int lr4 = (lane >> 4) * 4;
  const int tokb = b * 32 + t * 2 + hb;
  #pragma unroll
  for (int mf = 0; mf < 4; ++mf) {
    const int co0g = cb * 128 + wm * 64 + mf * 16 + lr4;
    const float4 bv = *(const float4*)(bias + co0g);
    const int kc = co0g >> 5, kq = (co0g >> 3) & 3, j0 = co0g & 7;
    #pragma unroll
    for (int nf = 0; nf < 2; ++nf) {
      const int n_l = wn * 32 + nf * 16 + lc;
      const size_t off = (size_t)(tokb * 16 + kc) * 4096 + kq * 1024 + n_l * 8 + j0;
      unsigned int p0 = splitpack(acc[mf][nf][0] + bv.x);
      unsigned int p1 = splitpack(acc[mf][nf][1] + bv.y);
      unsigned int p2 = splitpack(acc[mf][nf][2] + bv.z);
      unsigned int p3 = splitpack(acc[mf][nf][3] + bv.w);
      ushort4 h4, l4;
      h4.x = (unsigned short)(p0 & 0xffffu); l4.x = (unsigned short)(p0 >> 16);
      h4.y = (unsigned short)(p1 & 0xffffu); l4.y = (unsigned short)(p1 >> 16);
      h4.z = (unsigned short)(p2 & 0xffffu); l4.z = (unsigned short)(p2 >> 16);
      h4.w = (unsigned short)(p3 & 0xffffu); l4.w = (unsigned short)(p3 >> 16);
      *(ushort4*)(fhi + off) = h4;
      *(ushort4*)(flo + off) = l4;
    }
  }
}

// ---------------- VQ as MFMA GEMM (bf16x2) + fused argmin (unchanged) ----------------
__global__ __launch_bounds__(512) void vq_mfma_k(
    const unsigned short* __restrict__ fhi, const unsigned short* __restrict__ flo,
    const unsigned short* __restrict__ cbhi, const unsigned short* __restrict__ cblo,
    const float* __restrict__ c2,
    float* __restrict__ pval, int* __restrict__ pidx) {
  __shared__ __align__(16) unsigned short lds[16384];

  const int tid  = threadIdx.x;
  const int lane = tid & 63;
  const int wid  = tid >> 6;
  const int wm   = wid >> 2, wn = wid & 3;
  const int vb = blockIdx.x;
  const int tb = blockIdx.y;
  const int v0 = vb * 128, tok0 = tb * 128;

  const int lc = lane & 15, kgl = lane >> 4;
  const uint4* pAhi[4]; const uint4* pAlo[4];
  #pragma unroll
  for (int mf = 0; mf < 4; ++mf) {
    const int off = kgl * 1024 + (wm * 64 + mf * 16 + lc) * 8;
    pAhi[mf] = (const uint4*)&lds[off];
    pAlo[mf] = (const uint4*)&lds[4096 + off];
  }
  const uint4* pBhi[2]; const uint4* pBlo[2];
  #pragma unroll
  for (int nf = 0; nf < 2; ++nf) {
    const int off = kgl * 1024 + (wn * 32 + nf * 16 + lc) * 8;
    pBhi[nf] = (const uint4*)&lds[8192 + off];
    pBlo[nf] = (const uint4*)&lds[12288 + off];
  }
  uint4* wAhi = (uint4*)&lds[tid * 8];
  uint4* wAlo = (uint4*)&lds[4096 + tid * 8];
  uint4* wBhi = (uint4*)&lds[8192 + tid * 8];
  uint4* wBlo = (uint4*)&lds[12288 + tid * 8];

  f32x4 acc[4][2];
  #pragma unroll
  for (int mf = 0; mf < 4; ++mf)
    #pragma unroll
    for (int nf = 0; nf < 2; ++nf) acc[mf][nf] = (f32x4)(0.f);

  uint4 cah, cal, fbh, fbl;
  auto issue = [&](int kc) {
    const size_t cboff = (size_t)(vb * 16 + kc) * 4096 + tid * 8;
    const size_t foff  = (size_t)(tb * 16 + kc) * 4096 + tid * 8;
    cah = *(const uint4*)(cbhi + cboff);
    cal = *(const uint4*)(cblo + cboff);
    fbh = *(const uint4*)(fhi + foff);
    fbl = *(const uint4*)(flo + foff);
  };

  issue(0);

  for (int kc = 0; kc < 16; ++kc) {
    __syncthreads();
    *wAhi = cah;
    *wAlo = cal;
    *wBhi = fbh;
    *wBlo = fbl;
    __syncthreads();
    if (kc + 1 < 16) issue(kc + 1);

    uint4 ah[4], al[4], bh[2], bl[2];
    #pragma unroll
    for (int mf = 0; mf < 4; ++mf) { ah[mf] = *pAhi[mf]; al[mf] = *pAlo[mf]; }
    #pragma unroll
    for (int nf = 0; nf < 2; ++nf) { bh[nf] = *pBhi[nf]; bl[nf] = *pBlo[nf]; }

    #pragma unroll
    for (int mf = 0; mf < 4; ++mf)
      #pragma unroll
      for (int nf = 0; nf < 2; ++nf) mfma_bf16(acc[mf][nf], ah[mf], bh[nf]);
    #pragma unroll
    for (int mf = 0; mf < 4; ++mf)
      #pragma unroll
      for (int nf = 0; nf < 2; ++nf) mfma_bf16(acc[mf][nf], ah[mf], bl[nf]);
    #pragma unroll
    for (int mf = 0; mf < 4; ++mf)
      #pragma unroll
      for (int nf = 0; nf < 2; ++nf) mfma_bf16(acc[mf][nf], al[mf], bh[nf]);
  }

  float best[2]; int bidx[2];
  best[0] = best[1] = 3.4e38f; bidx[0] = bidx[1] = 0;
  #pragma unroll
  for (int mf = 0; mf < 4; ++mf) {
    float cc[4];
    *(float4*)cc = *(const float4*)(c2 + v0 + wm * 64 + mf * 16 + kgl * 4);
    #pragma unroll
    for (int nf = 0; nf < 2; ++nf) {
      #pragma unroll
      for (int r = 0; r < 4; ++r) {
        const float d = cc[r] - 2.f * acc[mf][nf][r];
        const int vg = v0 + wm * 64 + mf * 16 + kgl * 4 + r;
        if (d < best[nf] || (d == best[nf] && vg < bidx[nf])) { best[nf] = d; bidx[nf] = vg; }
      }
    }
  }
  #pragma unroll
  for (int off = 16; off <= 32; off <<= 1) {
    #pragma unroll
    for (int nf = 0; nf < 2; ++nf) {
      const float ov = __shfl_xor(best[nf], off);
      const int   oi = __shfl_xor(bidx[nf], off);
      if (ov < best[nf] || (ov == best[nf] && oi < bidx[nf])) { best[nf] = ov; bidx[nf] = oi; }
    }
  }
  if (lane < 16) {
    #pragma unroll
    for (int nf = 0; nf < 2; ++nf) {
      const int tok = tok0 + wn * 32 + nf * 16 + lane;
      const int slot = vb * 2 + wm;
      pval[(size_t)tok * 128 + slot] = best[nf];
      pidx[(size_t)tok * 128 + slot] = bidx[nf];
    }
  }
}

__global__ void vq_reduce_k(const float* __restrict__ pval, const int* __restrict__ pidx,
                            int* __restrict__ tokens, float* __restrict__ out_tok) {
  const int tok = blockIdx.x * blockDim.x + threadIdx.x;  // 8192
  float best = 3.4e38f; int bi = 0;
  for (int s = 0; s < 128; ++s) {
    const float v = pval[(size_t)tok * 128 + s];
    const int idx = pidx[(size_t)tok * 128 + s];
    if (v < best || (v == best && idx < bi)) { best = v; bi = idx; }
  }
  tokens[tok] = bi;
  out_tok[tok] = (float)bi;
}

__global__ void gather_k(const int* __restrict__ tokens, const float* __restrict__ emb,
                         float* __restrict__ out) {
  const int i = blockIdx.x * blockDim.x + threadIdx.x;  // 1,048,576 float4s
  const int n = i >> 7;
  const int c4 = (i & 127) * 4;
  const int tk = tokens[n];
  float4 v = *(const float4*)(emb + (size_t)tk * 512 + c4);
  *(float4*)(out + (size_t)n * 512 + c4) = v;
}

extern "C" void kernel_launch(void* const* d_in, const int* in_sizes, int n_in,
                              void* d_out, int out_size, void* d_ws, size_t ws_size,
                              hipStream_t stream) {
  const float* video = (const float*)d_in[0];
  const float* w1 = (const float*)d_in[1];
  const float* b1 = (const float*)d_in[2];
  const float* w2 = (const float*)d_in[3];
  const float* b2 = (const float*)d_in[4];
  const float* w3 = (const float*)d_in[5];
  const float* b3 = (const float*)d_in[6];
  const float* cb  = (const float*)d_in[7];
  const float* emb = (const float*)d_in[8];

  float* ws = (float*)d_ws;
  unsigned int* h1p = (unsigned int*)ws;
  unsigned short* fhi = (unsigned short*)(ws);
  unsigned short* flo = (unsigned short*)(ws + 2097152);
  unsigned short* cbhi = (unsigned short*)(ws + 4194304);
  unsigned short* cblo = (unsigned short*)(ws + 6291456);
  float* c2v  = ws + 8388608;
  float* pval = ws + 8396800;
  int*   pidx = (int*)(ws + 9445376);
  int*   tokens = (int*)(ws + 10493952);
  unsigned int* h2p = (unsigned int*)(ws + 16777216);
  unsigned short* w2hi = (unsigned short*)d_out;  //   884,736 ushorts
  unsigned short* w2lo = w2hi + 884736;
  unsigned short* w3hi = (unsigned short*)d_out;  // 3,538,944 ushorts
  unsigned short* w3lo = w3hi + 3538944;
  float* out_tok = (float*)d_out;
  float* out_emb = (float*)d_out + 8192;

  hipLaunchKernelGGL(conv1_k, dim3(4, 16, 32), dim3(16, 16), 0, stream, video, w1, b1, h1p);
  hipLaunchKernelGGL(split_w2_k, dim3(3456), dim3(256), 0, stream, w2, w2hi, w2lo);
  hipLaunchKernelGGL(conv2_mfma_k, dim3(512), dim3(512), 0, stream,
                     h1p, w2hi, w2lo, b2, h2p);
  // h1p dead; d_out w2 tiles dead -> w3 tiles
  hipLaunchKernelGGL(split_w3_k, dim3(13824), dim3(256), 0, stream, w3, w3hi, w3lo);
  hipLaunchKernelGGL(split_cb_k, dim3(16384), dim3(256), 0, stream, cb, cbhi, cblo);
  hipLaunchKernelGGL(c2_k, dim3(2048), dim3(256), 0, stream, cb, c2v);
  hipLaunchKernelGGL(conv3_mfma_k, dim3(256), dim3(512), 0, stream,
                     h2p, w3hi, w3lo, b3, fhi, flo);
  hipLaunchKernelGGL(vq_mfma_k, dim3(64, 64), dim3(512), 0, stream,
                     fhi, flo, cbhi, cblo, c2v, pval, pidx);
  hipLaunchKernelGGL(vq_reduce_k, dim3(32), dim3(256), 0, stream, pval, pidx, tokens, out_tok);
  hipLaunchKernelGGL(gather_k, dim3(4096), dim3(256), 0, stream, tokens, emb, out_emb);
}

// Round 7
// 749.131 us; speedup vs baseline: 1.0007x; 1.0007x over previous
//
#include <hip/hip_runtime.h>

typedef __bf16 bf16x8 __attribute__((ext_vector_type(8)));
typedef float  f32x4  __attribute__((ext_vector_type(4)));

// ---------------- bf16x2 split helper: pack(hi | lo<<16) ----------------
__device__ __forceinline__ unsigned int splitpack(float x) {
  unsigned int u = __float_as_uint(x);
  unsigned int hi = (u + 0x7fffu + ((u >> 16) & 1u)) >> 16;
  float l = x - __uint_as_float(hi << 16);
  unsigned int ul = __float_as_uint(l);
  unsigned int lo = (ul + 0x7fffu + ((ul >> 16) & 1u)) >> 16;
  return hi | (lo << 16);
}

__device__ __forceinline__ void mfma_bf16(f32x4& d, uint4 a, uint4 b) {
  d = __builtin_amdgcn_mfma_f32_16x16x32_bf16(
        __builtin_bit_cast(bf16x8, a), __builtin_bit_cast(bf16x8, b), d, 0, 0, 0);
}

// ======== layouts ========
// h1p u32: IDX1(b,g,t,pl,r,c,j) = b*8388608 + g*524288 + t*32768 + pl*8192 + (r*32+c)*8 + j
// h2p u32: IDX2(b,g,t,pl,r,c,j) = b*4194304 + g*131072 + t*8192 + pl*2048 + (r*16+c)*8 + j

// ---------------- conv1: VALU conv, epilogue writes j-grouped parity planes ------------
__global__ void conv1_k(const float* __restrict__ in, const float* __restrict__ wgt,
                        const float* __restrict__ bias, unsigned int* __restrict__ h1p) {
  const int tx = threadIdx.x;          // 0..15
  const int w0 = tx * 4;
  const int h  = blockIdx.x * 16 + threadIdx.y;  // 0..63
  const int co0 = blockIdx.y * 8;
  const int bz = blockIdx.z;
  const int b = bz >> 4, t = bz & 15;

  float acc[8][4];
  #pragma unroll
  for (int i = 0; i < 8; ++i) {
    const float bv = bias[co0 + i];
    #pragma unroll
    for (int j = 0; j < 4; ++j) acc[i][j] = bv;
  }
  const int cs = 2 * w0 - 2;

  for (int ci = 0; ci < 3; ++ci) {
    const float* inc = in + (size_t)((b * 3 + ci) * 16) * (128 * 128);
    const float* wc  = wgt + ((size_t)co0 * 3 + ci) * 27;
    #pragma unroll
    for (int kd = 0; kd < 3; ++kd) {
      const int t2 = t - 1 + kd;
      if (t2 < 0 || t2 >= 16) continue;
      const float* ip = inc + t2 * (128 * 128);
      #pragma unroll
      for (int kh = 0; kh < 3; ++kh) {
        const int hh = 2 * h - 1 + kh;
        float v[10];
        if (hh >= 0) {
          const float* r = ip + hh * 128 + cs;
          if (cs >= 0) { float2 u = *(const float2*)r; v[0] = u.x; v[1] = u.y; }
          else         { v[0] = 0.f; v[1] = 0.f; }
          float2 u1 = *(const float2*)(r + 2); v[2] = u1.x; v[3] = u1.y;
          float2 u2 = *(const float2*)(r + 4); v[4] = u2.x; v[5] = u2.y;
          float2 u3 = *(const float2*)(r + 6); v[6] = u3.x; v[7] = u3.y;
          float2 u4 = *(const float2*)(r + 8); v[8] = u4.x; v[9] = u4.y;
        } else {
          #pragma unroll
          for (int z = 0; z < 10; ++z) v[z] = 0.f;
        }
        #pragma unroll
        for (int i = 0; i < 8; ++i) {
          const float* wp = wc + (size_t)i * (3 * 27) + kd * 9 + kh * 3;
          const float wa = wp[0], wb = wp[1], wcc = wp[2];
          #pragma unroll
          for (int wi = 0; wi < 4; ++wi) {
            acc[i][wi] = fmaf(v[1 + 2*wi], wa,  acc[i][wi]);
            acc[i][wi] = fmaf(v[2 + 2*wi], wb,  acc[i][wi]);
            acc[i][wi] = fmaf(v[3 + 2*wi], wcc, acc[i][wi]);
          }
        }
      }
    }
  }
  const int ph = h & 1, rr = h >> 1, cc0 = tx * 2;
  const size_t base0 = (size_t)b * 8388608 + (size_t)blockIdx.y * 524288
                     + (size_t)t * 32768 + (size_t)(ph * 2) * 8192 + (size_t)rr * 256;
  #pragma unroll
  for (int i = 0; i < 8; ++i) {
    unsigned int p0 = splitpack(fmaxf(acc[i][0], 0.f));
    unsigned int p1 = splitpack(fmaxf(acc[i][1], 0.f));
    unsigned int p2 = splitpack(fmaxf(acc[i][2], 0.f));
    unsigned int p3 = splitpack(fmaxf(acc[i][3], 0.f));
    h1p[base0 + cc0 * 8 + i]              = p0;
    h1p[base0 + 8192 + cc0 * 8 + i]       = p1;
    h1p[base0 + (cc0 + 1) * 8 + i]        = p2;
    h1p[base0 + 8192 + (cc0 + 1) * 8 + i] = p3;
  }
}

// ---------------- w2 -> MFMA tiles [tap27][cic4][cbk2][kg4][col128][j8] ----------------
__global__ void split_w2_k(const float* __restrict__ w2, unsigned short* __restrict__ whi,
                           unsigned short* __restrict__ wlo) {
  unsigned int o = blockIdx.x * 256u + threadIdx.x;      // grid exact: 3456*256
  unsigned int j   = o & 7u;
  unsigned int col = (o >> 3) & 127u;
  unsigned int kg  = (o >> 10) & 3u;
  unsigned int cbk = (o >> 12) & 1u;
  unsigned int cic = (o >> 13) & 3u;
  unsigned int tap = o >> 15;
  unsigned int co = cbk * 128u + col, ci = cic * 32u + kg * 8u + j;
  float x = w2[((size_t)co * 128u + ci) * 27u + tap];
  unsigned int p = splitpack(x);
  whi[o] = (unsigned short)(p & 0xffffu);
  wlo[o] = (unsigned short)(p >> 16);
}

// ---------------- w3 -> MFMA tiles [tap27][cic8][cb4][kg4][col128][j8] ----------------
__global__ void split_w3_k(const float* __restrict__ w3, unsigned short* __restrict__ whi,
                           unsigned short* __restrict__ wlo) {
  unsigned int o = blockIdx.x * 256u + threadIdx.x;      // grid exact: 13824*256 = 27<<17
  unsigned int j   = o & 7u;
  unsigned int col = (o >> 3) & 127u;
  unsigned int kg  = (o >> 10) & 3u;
  unsigned int cb  = (o >> 12) & 3u;
  unsigned int cic = (o >> 14) & 7u;
  unsigned int tap = o >> 17;
  unsigned int co = cb * 128u + col, ci = cic * 32u + kg * 8u + j;
  float x = w3[((size_t)co * 256u + ci) * 27u + tap];
  unsigned int p = splitpack(x);
  whi[o] = (unsigned short)(p & 0xffffu);
  wlo[o] = (unsigned short)(p >> 16);
}

// ---------------- codebook -> tiled hi/lo ----------------
__global__ void split_cb_k(const float* __restrict__ cb, unsigned short* __restrict__ cbhi,
                           unsigned short* __restrict__ cblo) {
  unsigned int o = blockIdx.x * 256u + threadIdx.x;      // grid exact: 16384*256 = 2^22
  unsigned int j   = o & 7u;
  unsigned int row = (o >> 3) & 127u;
  unsigned int kq  = (o >> 10) & 3u;
  unsigned int kc  = (o >> 12) & 15u;
  unsigned int vb  = o >> 16;
  unsigned int v = vb * 128u + row, k = kc * 32u + kq * 8u + j;
  float x = cb[(size_t)v * 512u + k];
  unsigned int p = splitpack(x);
  cbhi[o] = (unsigned short)(p & 0xffffu);
  cblo[o] = (unsigned short)(p >> 16);
}

// ---------------- codebook squared norms ----------------
__global__ void c2_k(const float* __restrict__ cb, float* __restrict__ c2) {
  const int wid = threadIdx.x >> 6, lane = threadIdx.x & 63;
  const int v = blockIdx.x * 4 + wid;
  const float* row = cb + (size_t)v * 512 + lane * 8;
  float4 a = *(const float4*)row, b = *(const float4*)(row + 4);
  float s = a.x*a.x + a.y*a.y + a.z*a.z + a.w*a.w
          + b.x*b.x + b.y*b.y + b.z*b.z + b.w*b.w;
  #pragma unroll
  for (int off = 32; off; off >>= 1) s += __shfl_down(s, off);
  if (lane == 0) c2[v] = s;
}

// ---------------- conv2: MFMA, dbuf LDS, XCD-swizzled 1D grid (bt co-residency) -------
#define NCH2 108   // 27 taps * 4 ci-chunks of 32
#define BUFO 16384
__global__ __launch_bounds__(512) void conv2_mfma_k(
    const unsigned int* __restrict__ xp,
    const unsigned short* __restrict__ whi, const unsigned short* __restrict__ wlo,
    const float* __restrict__ bias,
    unsigned int* __restrict__ h2p) {
  __shared__ __align__(16) unsigned short lds[32768];

  const int tid  = threadIdx.x;
  const int lane = tid & 63;
  const int wid  = tid >> 6;
  const int wm   = wid >> 2, wn = wid & 3;
  const int bid = blockIdx.x;          // 0..511
  const int xcd = bid & 7;
  const int q   = bid >> 3;            // 0..63
  const int cbk = q & 1;
  const int nb  = (q >> 1) & 7;
  const int bt  = xcd + 8 * (q >> 4);  // q>>4 in 0..3
  const int b = bt >> 4, t = bt & 15;

  const int skg = tid >> 7;
  const int sn  = tid & 127;
  const int s_hout = nb * 4 + (sn >> 5);
  const int s_wout = sn & 31;

  const int lc = lane & 15, kgl = lane >> 4;

  f32x4 acc[4][2];
  #pragma unroll
  for (int mf = 0; mf < 4; ++mf)
    #pragma unroll
    for (int nf = 0; nf < 2; ++nf) acc[mf][nf] = (f32x4)(0.f);

  auto issue = [&](int ic, uint4& xa, uint4& xb, uint4& wh, uint4& wl) {
    const int tap = ic >> 2, cic = ic & 3;
    const int kd = tap / 9, r9 = tap % 9;
    const int kh = r9 / 3, kw = r9 % 3;
    const int tt = t + kd - 1;
    const int pl = ((kh != 1) ? 2 : 0) + ((kw != 1) ? 1 : 0);
    const int r  = s_hout + (kh != 0) - 1;
    const int c  = s_wout + (kw != 0) - 1;
    const bool oob = (tt < 0) || (tt > 15) || (r < 0) || (c < 0);
    const int o = b * 8388608 + (cic * 4 + skg) * 524288 + tt * 32768 + pl * 8192 + (r * 32 + c) * 8;
    const unsigned int* src = xp + (oob ? 0 : o);
    uint4 a = *(const uint4*)src, bb = *(const uint4*)(src + 4);
    if (oob) { a = make_uint4(0u,0u,0u,0u); bb = make_uint4(0u,0u,0u,0u); }
    xa = a; xb = bb;
    const size_t slab = ((size_t)((tap * 4 + cic) * 2 + cbk)) << 12;
    wh = *(const uint4*)(whi + slab + tid * 8);
    wl = *(const uint4*)(wlo + slab + tid * 8);
  };

  auto stage = [&](int bo, const uint4& xa, const uint4& xb, const uint4& wh, const uint4& wl) {
    *(uint4*)&lds[bo + tid * 8] = wh;
    *(uint4*)&lds[bo + 4096 + tid * 8] = wl;
    uint4 H, L;
    H.x = (xa.x & 0xffffu) | (xa.y << 16);  L.x = (xa.x >> 16) | (xa.y & 0xffff0000u);
    H.y = (xa.z & 0xffffu) | (xa.w << 16);  L.y = (xa.z >> 16) | (xa.w & 0xffff0000u);
    H.z = (xb.x & 0xffffu) | (xb.y << 16);  L.z = (xb.x >> 16) | (xb.y & 0xffff0000u);
    H.w = (xb.z & 0xffffu) | (xb.w << 16);  L.w = (xb.z >> 16) | (xb.w & 0xffff0000u);
    *(uint4*)&lds[bo + 8192  + (skg * 128 + sn) * 8] = H;
    *(uint4*)&lds[bo + 12288 + (skg * 128 + sn) * 8] = L;
  };

  auto mma = [&](int bo) {
    uint4 ah[4], al[4], bh[2], bl[2];
    #pragma unroll
    for (int mf = 0; mf < 4; ++mf) {
      const int o = bo + kgl * 1024 + (wm * 64 + mf * 16 + lc) * 8;
      ah[mf] = *(const uint4*)&lds[o];
      al[mf] = *(const uint4*)&lds[o + 4096];
    }
    #pragma unroll
    for (int nf = 0; nf < 2; ++nf) {
      const int o = bo + 8192 + kgl * 1024 + (wn * 32 + nf * 16 + lc) * 8;
      bh[nf] = *(const uint4*)&lds[o];
      bl[nf] = *(const uint4*)&lds[o + 4096];
    }
    #pragma unroll
    for (int mf = 0; mf < 4; ++mf)
      #pragma unroll
      for (int nf = 0; nf < 2; ++nf) mfma_bf16(acc[mf][nf], ah[mf], bh[nf]);
    #pragma unroll
    for (int mf = 0; mf < 4; ++mf)
      #pragma unroll
      for (int nf = 0; nf < 2; ++nf) mfma_bf16(acc[mf][nf], ah[mf], bl[nf]);
    #pragma unroll
    for (int mf = 0; mf < 4; ++mf)
      #pragma unroll
      for (int nf = 0; nf < 2; ++nf) mfma_bf16(acc[mf][nf], al[mf], bh[nf]);
  };

  uint4 xa0, xb0, wh0, wl0, xa1, xb1, wh1, wl1;
  issue(0, xa0, xb0, wh0, wl0);
  issue(1, xa1, xb1, wh1, wl1);

  #pragma unroll 1
  for (int ic = 0; ic < NCH2; ic += 2) {
    stage(0, xa0, xb0, wh0, wl0);
    __syncthreads();
    if (ic + 2 < NCH2) issue(ic + 2, xa0, xb0, wh0, wl0);
    mma(0);
    stage(BUFO, xa1, xb1, wh1, wl1);
    __syncthreads();
    if (ic + 3 < NCH2) issue(ic + 3, xa1, xb1, wh1, wl1);
    mma(BUFO);
  }

  const int lr4 = (lane >> 4) * 4;
  #pragma unroll
  for (int mf = 0; mf < 4; ++mf) {
    const int co0g = cbk * 128 + wm * 64 + mf * 16 + lr4;
    const float4 bv = *(const float4*)(bias + co0g);
    const float* bp = (const float*)&bv;
    const size_t gbase = (size_t)(b * 32 + (co0g >> 3)) * 131072 + (size_t)t * 8192 + (co0g & 7);
    #pragma unroll
    for (int nf = 0; nf < 2; ++nf) {
      const int n_l = wn * 32 + nf * 16 + lc;
      const int h_out = nb * 4 + (n_l >> 5);
      const int w_out = n_l & 31;
      const int pl_o = ((h_out & 1) << 1) | (w_out & 1);
      const size_t sp = gbase + (size_t)pl_o * 2048 + (size_t)((h_out >> 1) * 16 + (w_out >> 1)) * 8;
      #pragma unroll
      for (int r = 0; r < 4; ++r) {
        const float x = fmaxf(acc[mf][nf][r] + bp[r], 0.f);
        h2p[sp + r] = splitpack(x);
      }
    }
  }
}

// ---------------- conv3: MFMA 64co x 128tok, 256 thr, 2 blocks/CU, dbuf LDS ----------
#define NCH 216   // 27 taps * 8 ci-chunks of 32
#define BUF3 12288
__global__ __launch_bounds__(256, 2) void conv3_mfma_k(
    const unsigned int* __restrict__ xp,
    const unsigned short* __restrict__ whi, const unsigned short* __restrict__ wlo,
    const float* __restrict__ bias,
    unsigned short* __restrict__ fhi, unsigned short* __restrict__ flo) {
  // per buffer (ushort): Ahi [0,2048) Alo [2048,4096) Bhi [4096,8192) Blo [8192,12288)
  __shared__ __align__(16) unsigned short lds[24576];   // 2 x 24 KB

  const int tid  = threadIdx.x;        // 0..255
  const int lane = tid & 63;
  const int wn   = tid >> 6;           // 4 waves over N
  // XCD swizzle: bid%8 -> bt-group
  const int bid = blockIdx.x;          // 0..511
  const int xcd = bid & 7;
  const int q   = bid >> 3;            // 0..63
  const int cb8 = q & 7;               // co block of 64
  const int hb  = (q >> 3) & 1;
  const int bt  = xcd + 8 * (q >> 4);  // q>>4 in 0..3
  const int b = bt >> 4, t = bt & 15;

  // x stager: thread covers (kg=skg, tok=stok) and (kg=skg+2, tok=stok)
  const int stok = tid & 127;
  const int skg  = tid >> 7;           // 0..1
  const int shn = hb * 8 + (stok >> 4);
  const int swn = stok & 15;
  // w stager: thread -> (kg=tid>>6, col=tid&63)
  const int cb = cb8 >> 1, cb64 = (cb8 & 1) * 64;
  const int woff = ((tid >> 6) * 128 + cb64 + (tid & 63)) * 8;

  const int lc = lane & 15, kgl = lane >> 4;

  f32x4 acc[4][2];
  #pragma unroll
  for (int mf = 0; mf < 4; ++mf)
    #pragma unroll
    for (int nf = 0; nf < 2; ++nf) acc[mf][nf] = (f32x4)(0.f);

  auto issue = [&](int ic, uint4& x0a, uint4& x0b, uint4& x1a, uint4& x1b,
                   uint4& wh, uint4& wl) {
    const int tap = ic >> 3, cic = ic & 7;
    const int kd = tap / 9, r9 = tap % 9;
    const int kh = r9 / 3, kw = r9 % 3;
    const int tt = t + kd - 1;
    const int pl = ((kh != 1) ? 2 : 0) + ((kw != 1) ? 1 : 0);
    const int r  = shn + (kh != 0) - 1;
    const int c  = swn + (kw != 0) - 1;
    const bool oob = (tt < 0) || (tt > 15) || (r < 0) || (c < 0);
    const int o0 = b * 4194304 + (cic * 4 + skg) * 131072 + tt * 8192 + pl * 2048 + (r * 16 + c) * 8;
    const unsigned int* s0 = xp + (oob ? 0 : o0);
    const unsigned int* s1 = xp + (oob ? 0 : (o0 + 262144));
    uint4 a0 = *(const uint4*)s0, b0 = *(const uint4*)(s0 + 4);
    uint4 a1 = *(const uint4*)s1, b1 = *(const uint4*)(s1 + 4);
    if (oob) {
      a0 = make_uint4(0u,0u,0u,0u); b0 = make_uint4(0u,0u,0u,0u);
      a1 = make_uint4(0u,0u,0u,0u); b1 = make_uint4(0u,0u,0u,0u);
    }
    x0a = a0; x0b = b0; x1a = a1; x1b = b1;
    const size_t slab = ((size_t)((tap * 8 + cic) * 4 + cb)) << 12;
    wh = *(const uint4*)(whi + slab + woff);
    wl = *(const uint4*)(wlo + slab + woff);
  };

  auto stage = [&](int bo, const uint4& x0a, const uint4& x0b,
                   const uint4& x1a, const uint4& x1b,
                   const uint4& wh, const uint4& wl) {
    *(uint4*)&lds[bo + tid * 8] = wh;            // A layout: (kg*64+col)*8 == tid*8
    *(uint4*)&lds[bo + 2048 + tid * 8] = wl;
    uint4 H0, L0, H1, L1;
    H0.x = (x0a.x & 0xffffu) | (x0a.y << 16);  L0.x = (x0a.x >> 16) | (x0a.y & 0xffff0000u);
    H0.y = (x0a.z & 0xffffu) | (x0a.w << 16);  L0.y = (x0a.z >> 16) | (x0a.w & 0xffff0000u);
    H0.z = (x0b.x & 0xffffu) | (x0b.y << 16);  L0.z = (x0b.x >> 16) | (x0b.y & 0xffff0000u);
    H0.w = (x0b.z & 0xffffu) | (x0b.w << 16);  L0.w = (x0b.z >> 16) | (x0b.w & 0xffff0000u);
    H1.x = (x1a.x & 0xffffu) | (x1a.y << 16);  L1.x = (x1a.x >> 16) | (x1a.y & 0xffff0000u);
    H1.y = (x1a.z & 0xffffu) | (x1a.w << 16);  L1.y = (x1a.z >> 16) | (x1a.w & 0xffff0000u);
    H1.z = (x1b.x & 0xffffu) | (x1b.y << 16);  L1.z = (x1b.x >> 16) | (x1b.y & 0xffff0000u);
    H1.w = (x1b.z & 0xffffu) | (x1b.w << 16);  L1.w = (x1b.z >> 16) | (x1b.w & 0xffff0000u);
    // B layout: (kg*128+tok)*8; pair0 index = tid, pair1 index = tid+256
    *(uint4*)&lds[bo + 4096 + tid * 8]          = H0;
    *(uint4*)&lds[bo + 4096 + (tid + 256) * 8]  = H1;
    *(uint4*)&lds[bo + 8192 + tid * 8]          = L0;
    *(uint4*)&lds[bo + 8192 + (tid + 256) * 8]  = L1;
  };

  auto mma = [&](int bo) {
    uint4 ah[4], al[4], bh[2], bl[2];
    #pragma unroll
    for (int mf = 0; mf < 4; ++mf) {
      const int o = bo + kgl * 512 + (mf * 16 + lc) * 8;
      ah[mf] = *(const uint4*)&lds[o];
      al[mf] = *(const uint4*)&lds[o + 2048];
    }
    #pragma unroll
    for (int nf = 0; nf < 2; ++nf) {
      const int o = bo + 4096 + kgl * 1024 + (wn * 32 + nf * 16 + lc) * 8;
      bh[nf] = *(const uint4*)&lds[o];
      bl[nf] = *(const uint4*)&lds[o + 4096];
    }
    #pragma unroll
    for (int mf = 0; mf < 4; ++mf)
      #pragma unroll
      for (int nf = 0; nf < 2; ++nf) mfma_bf16(acc[mf][nf], ah[mf], bh[nf]);
    #pragma unroll
    for (int mf = 0; mf < 4; ++mf)
      #pragma unroll
      for (int nf = 0; nf < 2; ++nf) mfma_bf16(acc[mf][nf], ah[mf], bl[nf]);
    #pragma unroll
    for (int mf = 0; mf < 4; ++mf)
      #pragma unroll
      for (int nf = 0; nf < 2; ++nf) mfma_bf16(acc[mf][nf], al[mf], bh[nf]);
  };

  uint4 p0xa, p0xb, p0ya, p0yb, p0wh, p0wl;
  uint4 p1xa, p1xb, p1ya, p1yb, p1wh, p1wl;
  issue(0, p0xa, p0xb, p0ya, p0yb, p0wh, p0wl);
  issue(1, p1xa, p1xb, p1ya, p1yb, p1wh, p1wl);

  #pragma unroll 1
  for (int ic = 0; ic < NCH; ic += 2) {
    stage(0, p0xa, p0xb, p0ya, p0yb, p0wh, p0wl);
    __syncthreads();
    if (ic + 2 < NCH) issue(ic + 2, p0xa, p0xb, p0ya, p0yb, p0wh, p0wl);
    mma(0);
    stage(BUF3, p1xa, p1xb, p1ya, p1yb, p1wh, p1wl);
    __syncthreads();
    if (ic + 3 < NCH) issue(ic + 3, p1xa, p1xb, p1ya, p1yb, p1wh, p1wl);
    mma(BUF3);
  }

  // epilogue: bias add, bf16x2 split, store into tiled feature layout
  const int lr4 = (lane >> 4) * 4;
  const int tokb = b * 32 + t * 2 + hb;
  #pragma unroll
  for (int mf = 0; mf < 4; ++mf) {
    const int co0g = cb8 * 64 + mf * 16 + lr4;
    const float4 bv = *(const float4*)(bias + co0g);
    const int kc = co0g >> 5, kq = (co0g >> 3) & 3, j0 = co0g & 7;
    #pragma unroll
    for (int nf = 0; nf < 2; ++nf) {
      const int n_l = wn * 32 + nf * 16 + lc;
      const size_t off = (size_t)(tokb * 16 + kc) * 4096 + kq * 1024 + n_l * 8 + j0;
      unsigned int p0 = splitpack(acc[mf][nf][0] + bv.x);
      unsigned int p1 = splitpack(acc[mf][nf][1] + bv.y);
      unsigned int p2 = splitpack(acc[mf][nf][2] + bv.z);
      unsigned int p3 = splitpack(acc[mf][nf][3] + bv.w);
      ushort4 h4, l4;
      h4.x = (unsigned short)(p0 & 0xffffu); l4.x = (unsigned short)(p0 >> 16);
      h4.y = (unsigned short)(p1 & 0xffffu); l4.y = (unsigned short)(p1 >> 16);
      h4.z = (unsigned short)(p2 & 0xffffu); l4.z = (unsigned short)(p2 >> 16);
      h4.w = (unsigned short)(p3 & 0xffffu); l4.w = (unsigned short)(p3 >> 16);
      *(ushort4*)(fhi + off) = h4;
      *(ushort4*)(flo + off) = l4;
    }
  }
}

// ---------------- VQ as MFMA GEMM (bf16x2) + fused argmin (unchanged) ----------------
__global__ __launch_bounds__(512) void vq_mfma_k(
    const unsigned short* __restrict__ fhi, const unsigned short* __restrict__ flo,
    const unsigned short* __restrict__ cbhi, const unsigned short* __restrict__ cblo,
    const float* __restrict__ c2,
    float* __restrict__ pval, int* __restrict__ pidx) {
  __shared__ __align__(16) unsigned short lds[16384];

  const int tid  = threadIdx.x;
  const int lane = tid & 63;
  const int wid  = tid >> 6;
  const int wm   = wid >> 2, wn = wid & 3;
  const int vb = blockIdx.x;
  const int tb = blockIdx.y;
  const int v0 = vb * 128, tok0 = tb * 128;

  const int lc = lane & 15, kgl = lane >> 4;
  const uint4* pAhi[4]; const uint4* pAlo[4];
  #pragma unroll
  for (int mf = 0; mf < 4; ++mf) {
    const int off = kgl * 1024 + (wm * 64 + mf * 16 + lc) * 8;
    pAhi[mf] = (const uint4*)&lds[off];
    pAlo[mf] = (const uint4*)&lds[4096 + off];
  }
  const uint4* pBhi[2]; const uint4* pBlo[2];
  #pragma unroll
  for (int nf = 0; nf < 2; ++nf) {
    const int off = kgl * 1024 + (wn * 32 + nf * 16 + lc) * 8;
    pBhi[nf] = (const uint4*)&lds[8192 + off];
    pBlo[nf] = (const uint4*)&lds[12288 + off];
  }
  uint4* wAhi = (uint4*)&lds[tid * 8];
  uint4* wAlo = (uint4*)&lds[4096 + tid * 8];
  uint4* wBhi = (uint4*)&lds[8192 + tid * 8];
  uint4* wBlo = (uint4*)&lds[12288 + tid * 8];

  f32x4 acc[4][2];
  #pragma unroll
  for (int mf = 0; mf < 4; ++mf)
    #pragma unroll
    for (int nf = 0; nf < 2; ++nf) acc[mf][nf] = (f32x4)(0.f);

  uint4 cah, cal, fbh, fbl;
  auto issue = [&](int kc) {
    const size_t cboff = (size_t)(vb * 16 + kc) * 4096 + tid * 8;
    const size_t foff  = (size_t)(tb * 16 + kc) * 4096 + tid * 8;
    cah = *(const uint4*)(cbhi + cboff);
    cal = *(const uint4*)(cblo + cboff);
    fbh = *(const uint4*)(fhi + foff);
    fbl = *(const uint4*)(flo + foff);
  };

  issue(0);

  for (int kc = 0; kc < 16; ++kc) {
    __syncthreads();
    *wAhi = cah;
    *wAlo = cal;
    *wBhi = fbh;
    *wBlo = fbl;
    __syncthreads();
    if (kc + 1 < 16) issue(kc + 1);

    uint4 ah[4], al[4], bh[2], bl[2];
    #pragma unroll
    for (int mf = 0; mf < 4; ++mf) { ah[mf] = *pAhi[mf]; al[mf] = *pAlo[mf]; }
    #pragma unroll
    for (int nf = 0; nf < 2; ++nf) { bh[nf] = *pBhi[nf]; bl[nf] = *pBlo[nf]; }

    #pragma unroll
    for (int mf = 0; mf < 4; ++mf)
      #pragma unroll
      for (int nf = 0; nf < 2; ++nf) mfma_bf16(acc[mf][nf], ah[mf], bh[nf]);
    #pragma unroll
    for (int mf = 0; mf < 4; ++mf)
      #pragma unroll
      for (int nf = 0; nf < 2; ++nf) mfma_bf16(acc[mf][nf], ah[mf], bl[nf]);
    #pragma unroll
    for (int mf = 0; mf < 4; ++mf)
      #pragma unroll
      for (int nf = 0; nf < 2; ++nf) mfma_bf16(acc[mf][nf], al[mf], bh[nf]);
  }

  float best[2]; int bidx[2];
  best[0] = best[1] = 3.4e38f; bidx[0] = bidx[1] = 0;
  #pragma unroll
  for (int mf = 0; mf < 4; ++mf) {
    float cc[4];
    *(float4*)cc = *(const float4*)(c2 + v0 + wm * 64 + mf * 16 + kgl * 4);
    #pragma unroll
    for (int nf = 0; nf < 2; ++nf) {
      #pragma unroll
      for (int r = 0; r < 4; ++r) {
        const float d = cc[r] - 2.f * acc[mf][nf][r];
        const int vg = v0 + wm * 64 + mf * 16 + kgl * 4 + r;
        if (d < best[nf] || (d == best[nf] && vg < bidx[nf])) { best[nf] = d; bidx[nf] = vg; }
      }
    }
  }
  #pragma unroll
  for (int off = 16; off <= 32; off <<= 1) {
    #pragma unroll
    for (int nf = 0; nf < 2; ++nf) {
      const float ov = __shfl_xor(best[nf], off);
      const int   oi = __shfl_xor(bidx[nf], off);
      if (ov < best[nf] || (ov == best[nf] && oi < bidx[nf])) { best[nf] = ov; bidx[nf] = oi; }
    }
  }
  if (lane < 16) {
    #pragma unroll
    for (int nf = 0; nf < 2; ++nf) {
      const int tok = tok0 + wn * 32 + nf * 16 + lane;
      const int slot = vb * 2 + wm;
      pval[(size_t)tok * 128 + slot] = best[nf];
      pidx[(size_t)tok * 128 + slot] = bidx[nf];
    }
  }
}

__global__ void vq_reduce_k(const float* __restrict__ pval, const int* __restrict__ pidx,
                            int* __restrict__ tokens, float* __restrict__ out_tok) {
  const int tok = blockIdx.x * blockDim.x + threadIdx.x;  // 8192
  float best = 3.4e38f; int bi = 0;
  for (int s = 0; s < 128; ++s) {
    const float v = pval[(size_t)tok * 128 + s];
    const int idx = pidx[(size_t)tok * 128 + s];
    if (v < best || (v == best && idx < bi)) { best = v; bi = idx; }
  }
  tokens[tok] = bi;
  out_tok[tok] = (float)bi;
}

__global__ void gather_k(const int* __restrict__ tokens, const float* __restrict__ emb,
                         float* __restrict__ out) {
  const int i = blockIdx.x * blockDim.x + threadIdx.x;  // 1,048,576 float4s
  const int n = i >> 7;
  const int c4 = (i & 127) * 4;
  const int tk = tokens[n];
  float4 v = *(const float4*)(emb + (size_t)tk * 512 + c4);
  *(float4*)(out + (size_t)n * 512 + c4) = v;
}

extern "C" void kernel_launch(void* const* d_in, const int* in_sizes, int n_in,
                              void* d_out, int out_size, void* d_ws, size_t ws_size,
                              hipStream_t stream) {
  const float* video = (const float*)d_in[0];
  const float* w1 = (const float*)d_in[1];
  const float* b1 = (const float*)d_in[2];
  const float* w2 = (const float*)d_in[3];
  const float* b2 = (const float*)d_in[4];
  const float* w3 = (const float*)d_in[5];
  const float* b3 = (const float*)d_in[6];
  const float* cb  = (const float*)d_in[7];
  const float* emb = (const float*)d_in[8];

  float* ws = (float*)d_ws;
  unsigned int* h1p = (unsigned int*)ws;
  unsigned short* fhi = (unsigned short*)(ws);
  unsigned short* flo = (unsigned short*)(ws + 2097152);
  unsigned short* cbhi = (unsigned short*)(ws + 4194304);
  unsigned short* cblo = (unsigned short*)(ws + 6291456);
  float* c2v  = ws + 8388608;
  float* pval = ws + 8396800;
  int*   pidx = (int*)(ws + 9445376);
  int*   tokens = (int*)(ws + 10493952);
  unsigned int* h2p = (unsigned int*)(ws + 16777216);
  unsigned short* w2hi = (unsigned short*)d_out;  //   884,736 ushorts
  unsigned short* w2lo = w2hi + 884736;
  unsigned short* w3hi = (unsigned short*)d_out;  // 3,538,944 ushorts
  unsigned short* w3lo = w3hi + 3538944;
  float* out_tok = (float*)d_out;
  float* out_emb = (float*)d_out + 8192;

  hipLaunchKernelGGL(conv1_k, dim3(4, 16, 32), dim3(16, 16), 0, stream, video, w1, b1, h1p);
  hipLaunchKernelGGL(split_w2_k, dim3(3456), dim3(256), 0, stream, w2, w2hi, w2lo);
  hipLaunchKernelGGL(conv2_mfma_k, dim3(512), dim3(512), 0, stream,
                     h1p, w2hi, w2lo, b2, h2p);
  // h1p dead; d_out w2 tiles dead -> w3 tiles
  hipLaunchKernelGGL(split_w3_k, dim3(13824), dim3(256), 0, stream, w3, w3hi, w3lo);
  hipLaunchKernelGGL(split_cb_k, dim3(16384), dim3(256), 0, stream, cb, cbhi, cblo);
  hipLaunchKernelGGL(c2_k, dim3(2048), dim3(256), 0, stream, cb, c2v);
  hipLaunchKernelGGL(conv3_mfma_k, dim3(512), dim3(256), 0, stream,
                     h2p, w3hi, w3lo, b3, fhi, flo);
  hipLaunchKernelGGL(vq_mfma_k, dim3(64, 64), dim3(512), 0, stream,
                     fhi, flo, cbhi, cblo, c2v, pval, pidx);
  hipLaunchKernelGGL(vq_reduce_k, dim3(32), dim3(256), 0, stream, pval, pidx, tokens, out_tok);
  hipLaunchKernelGGL(gather_k, dim3(4096), dim3(256), 0, stream, tokens, emb, out_emb);
}